// Round 1
// baseline (4963.165 us; speedup 1.0000x reference)
//
#include <hip/hip_runtime.h>
#include <math.h>

#define B_ 16
#define T_ 4096
#define D_ 512
#define T1_ 4097

#define TT 32          // t-tile per block (rows of conv output)
#define IC 4           // i-chunk size for W staging
#define NTHR 512

#define SMOOTH_FACTOR 1.0
#define NOISE_THRESHOLD 0.0
#define TAIL_THRESHOLD 0.45

// ---- workspace layout (bytes) ----
#define WT_OFF   ((size_t)0)         // f64 Wt[k][i][o]: 3*512*512*8 = 6291456
#define PART_OFF ((size_t)6291456)   // f64 partial[b][t][2]: 16*4096*2*8 = 1048576
#define A32_OFF  ((size_t)7340032)   // f32 alpha[b][T1]: 16*4097*4 = 262208
#define FT_OFF   ((size_t)7602240)   // i32 fire_t[b][T1]: 262208
#define FF_OFF   ((size_t)7864448)   // f64 fire_frac[b][T1]: 524416
#define LEN_OFF  ((size_t)8388864)   // i32 batch_len[b]: 64

// ================= K0: conv_w [o][i][k] f32 -> Wt [k][i][o] f64 =================
__global__ void k_wt(const float* __restrict__ cw, double* __restrict__ wt) {
    int idx = blockIdx.x * 256 + threadIdx.x;
    if (idx >= 3 * D_ * D_) return;
    int o = idx & (D_ - 1);
    int r = idx >> 9;            // k*512 + i
    int i = r & (D_ - 1);
    int k = r >> 9;
    wt[idx] = (double)cw[(o * D_ + i) * 3 + k];
}

// ================= K1: f64 conv + fused relu-dot partial reduction =================
// grid (T_/TT, B_), 512 threads. Thread: 8 t x 4 o (o = og + 128*j, og = tid&127).
// Writes partial[b][t][half] where half = (tid>>6)&1 (two 64-lane o-halves).
__global__ __launch_bounds__(NTHR, 2)
void k_conv(const float* __restrict__ h, const double* __restrict__ wt,
            const float* __restrict__ cb, const float* __restrict__ ow,
            double* __restrict__ part) {
    extern __shared__ char smem[];
    float*  hs  = (float*)smem;                          // [TT+2][512] f32
    double* wls = (double*)(smem + (TT + 2) * D_ * 4);   // [3][IC][512] f64

    const int tid = threadIdx.x;
    const int b   = blockIdx.y;
    const int t0  = blockIdx.x * TT;
    const int og  = tid & 127;
    const int tg  = tid >> 7;      // 0..3, 8 t's each

    // stage h rows t0-1 .. t0+TT into LDS (zero-padded outside [0,T))
    const int NR = TT + 2;
    for (int idx = tid; idx < NR * (D_ / 4); idx += NTHR) {
        int row = idx >> 7;
        int c4  = idx & 127;
        int t   = t0 - 1 + row;
        float4 v = make_float4(0.f, 0.f, 0.f, 0.f);
        if (t >= 0 && t < T_)
            v = *(const float4*)(h + ((size_t)b * T_ + t) * D_ + (c4 << 2));
        *(float4*)(hs + row * D_ + (c4 << 2)) = v;
    }

    double acc[8][4];
    #pragma unroll
    for (int a = 0; a < 8; ++a)
        #pragma unroll
        for (int j = 0; j < 4; ++j) acc[a][j] = 0.0;

    auto wt_idx = [](int i0, int lin) -> size_t {
        int o  = lin & 511;
        int r  = lin >> 9;        // k*IC + ii
        int k  = r >> 2;
        int ii = r & 3;
        return ((size_t)(k * D_ + i0 + ii)) * D_ + o;
    };

    // prefetch W chunk 0 into registers
    double wreg[12];
    #pragma unroll
    for (int s = 0; s < 12; ++s) wreg[s] = wt[wt_idx(0, tid + s * NTHR)];

    for (int icb = 0; icb < D_ / IC; ++icb) {
        __syncthreads();   // previous chunk's readers done -> safe to overwrite wls
        #pragma unroll
        for (int s = 0; s < 12; ++s) wls[tid + s * NTHR] = wreg[s];
        if (icb + 1 < D_ / IC) {
            const int i0n = (icb + 1) * IC;
            #pragma unroll
            for (int s = 0; s < 12; ++s) wreg[s] = wt[wt_idx(i0n, tid + s * NTHR)];
        }
        __syncthreads();   // wls ready

        const int i0 = icb * IC;
        double hd[10][IC];
        #pragma unroll
        for (int rr = 0; rr < 10; ++rr) {
            float4 hv = *(const float4*)(hs + (tg * 8 + rr) * D_ + i0);
            hd[rr][0] = (double)hv.x; hd[rr][1] = (double)hv.y;
            hd[rr][2] = (double)hv.z; hd[rr][3] = (double)hv.w;
        }
        #pragma unroll
        for (int k = 0; k < 3; ++k) {
            #pragma unroll
            for (int ii = 0; ii < IC; ++ii) {
                double wd[4];
                #pragma unroll
                for (int j = 0; j < 4; ++j)
                    wd[j] = wls[((k * IC + ii) << 9) + og + (j << 7)];
                #pragma unroll
                for (int lt = 0; lt < 8; ++lt) {
                    #pragma unroll
                    for (int j = 0; j < 4; ++j)
                        acc[lt][j] = fma(hd[lt + k][ii], wd[j], acc[lt][j]);
                }
            }
        }
    }

    // epilogue: p(t) = sum_j out_w[o]*relu(z+conv_b[o]); wave-reduce over 64 lanes
    double cbv[4], owv[4];
    #pragma unroll
    for (int j = 0; j < 4; ++j) {
        cbv[j] = (double)cb[og + (j << 7)];
        owv[j] = (double)ow[og + (j << 7)];
    }
    const int half = (tid >> 6) & 1;
    #pragma unroll
    for (int lt = 0; lt < 8; ++lt) {
        double p = 0.0;
        #pragma unroll
        for (int j = 0; j < 4; ++j) {
            double z = acc[lt][j] + cbv[j];
            z = z > 0.0 ? z : 0.0;
            p = fma(owv[j], z, p);
        }
        #pragma unroll
        for (int off = 32; off > 0; off >>= 1) p += __shfl_xor(p, off);
        if ((tid & 63) == 0)
            part[(((size_t)b * T_) + t0 + tg * 8 + lt) * 2 + half] = p;
    }
}

// ================= K2: per-batch alpha finish + wave prefix-scan + fire records ====
// grid (B_), 64 threads (one wave per batch)
__global__ void k_scan(const double* __restrict__ part, const float* __restrict__ mask,
                       const float* __restrict__ outb,
                       float* __restrict__ out_tok, float* __restrict__ out_alpha,
                       float* __restrict__ a32, int* __restrict__ fire_t,
                       double* __restrict__ fire_frac, int* __restrict__ blen) {
    const int b = blockIdx.x;
    const int lane = threadIdx.x;
    const double ob = (double)outb[0];
    double carry = 0.0;
    int nf = 0;

    for (int c = 0; c < 65; ++c) {
        int t = c * 64 + lane;
        double a = 0.0;
        if (t < T_) {
            double o = part[((size_t)b * T_ + t) * 2] +
                       part[((size_t)b * T_ + t) * 2 + 1] + ob;
            double s = 1.0 / (1.0 + exp(-o));
            double ap = s * SMOOTH_FACTOR - NOISE_THRESHOLD;
            if (ap < 0.0) ap = 0.0;
            double mk = (double)mask[b * T_ + t];
            double mprev = (t == 0) ? 1.0 : (double)mask[b * T_ + t - 1];
            a = ap * mk + TAIL_THRESHOLD * (mprev - mk);
        } else if (t == T_) {
            double mprev = (double)mask[b * T_ + T_ - 1];
            a = TAIL_THRESHOLD * mprev;   // (mask_2[T]-mask_1[T])*0.45
        }
        if (t <= T_) {
            out_alpha[(size_t)b * T1_ + t] = (float)a;
            a32[(size_t)b * T1_ + t] = (float)a;
        }
        // inclusive wave prefix sum
        double x = a;
        #pragma unroll
        for (int off = 1; off < 64; off <<= 1) {
            double y = __shfl_up(x, off);
            if (lane >= off) x += y;
        }
        double ps = carry + x;
        double ps_prev = __shfl_up(ps, 1);
        if (lane == 0) ps_prev = carry;
        double psf = floor(ps), ppsf = floor(ps_prev);
        bool fire = (t <= T_) && (psf > ppsf);
        unsigned long long m = __ballot(fire);
        if (fire) {
            int k = nf + (int)__popcll(m & ((1ull << lane) - 1ull));
            fire_t[(size_t)b * T1_ + k] = t;
            fire_frac[(size_t)b * T1_ + k] = ps - psf;
        }
        nf += (int)__popcll(m);
        carry = __shfl(ps, 63);
    }
    if (lane == 0) {
        blen[b] = nf;
        out_tok[b] = (float)floor(carry);
    }
}

// ================= K3: frame construction =================
// grid (K, B_), 128 threads; each block builds acoustic[b][k][0..511]
__global__ void k_frames(const float* __restrict__ h, const float* __restrict__ a32,
                         const int* __restrict__ fire_t, const double* __restrict__ fire_frac,
                         const int* __restrict__ blen, float* __restrict__ out, int K) {
    const int k = blockIdx.x;
    const int b = blockIdx.y;
    const int tid = threadIdx.x;
    float4 acc = make_float4(0.f, 0.f, 0.f, 0.f);
    const int len = blen[b];
    if (k < len) {
        const int t1 = fire_t[(size_t)b * T1_ + k];
        const int t0 = (k > 0) ? fire_t[(size_t)b * T1_ + k - 1] : -1;
        const float f1 = (float)fire_frac[(size_t)b * T1_ + k];
        const float f0 = (k > 0) ? (float)fire_frac[(size_t)b * T1_ + k - 1] : 0.f;
        if (t0 >= 0 && t0 < T_) {
            float4 hv = *(const float4*)(h + ((size_t)b * T_ + t0) * D_ + (tid << 2));
            acc.x += f0 * hv.x; acc.y += f0 * hv.y; acc.z += f0 * hv.z; acc.w += f0 * hv.w;
        }
        for (int t = t0 + 1; t <= t1; ++t) {
            if (t >= T_) break;   // h row T_ is the implicit zero row
            float c = a32[(size_t)b * T1_ + t] - ((t == t1) ? f1 : 0.f);
            float4 hv = *(const float4*)(h + ((size_t)b * T_ + t) * D_ + (tid << 2));
            acc.x += c * hv.x; acc.y += c * hv.y; acc.z += c * hv.z; acc.w += c * hv.w;
        }
    }
    *(float4*)(out + ((size_t)b * K + k) * D_ + (tid << 2)) = acc;
}

// ================= host =================
extern "C" void kernel_launch(void* const* d_in, const int* in_sizes, int n_in,
                              void* d_out, int out_size, void* d_ws, size_t ws_size,
                              hipStream_t stream) {
    const float* h    = (const float*)d_in[0];
    const float* mask = (const float*)d_in[1];
    const float* cw   = (const float*)d_in[2];
    const float* cb   = (const float*)d_in[3];
    const float* ow   = (const float*)d_in[4];
    const float* ob   = (const float*)d_in[5];

    char* ws = (char*)d_ws;
    double* wt        = (double*)(ws + WT_OFF);
    double* part      = (double*)(ws + PART_OFF);
    float*  a32       = (float*)(ws + A32_OFF);
    int*    fire_t    = (int*)(ws + FT_OFF);
    double* fire_frac = (double*)(ws + FF_OFF);
    int*    blen      = (int*)(ws + LEN_OFF);

    // out layout: acoustic [B,K,D] | token_num [B] | alphas [B,T1]
    long long K = ((long long)out_size - B_ - (long long)B_ * T1_) / ((long long)B_ * D_);
    if (K < 1) K = 1;
    float* out_ac    = (float*)d_out;
    float* out_tok   = out_ac + (size_t)B_ * K * D_;
    float* out_alpha = out_tok + B_;

    const size_t lds = (size_t)(TT + 2) * D_ * 4 + (size_t)3 * IC * D_ * 8; // 118784
    (void)hipFuncSetAttribute((const void*)k_conv,
                              hipFuncAttributeMaxDynamicSharedMemorySize, (int)lds);

    k_wt<<<dim3((3 * D_ * D_ + 255) / 256), dim3(256), 0, stream>>>(cw, wt);
    k_conv<<<dim3(T_ / TT, B_), dim3(NTHR), lds, stream>>>(h, wt, cb, ow, part);
    k_scan<<<dim3(B_), dim3(64), 0, stream>>>(part, mask, ob, out_tok, out_alpha,
                                              a32, fire_t, fire_frac, blen);
    k_frames<<<dim3((unsigned)K, B_), dim3(128), 0, stream>>>(h, a32, fire_t, fire_frac,
                                                              blen, out_ac, (int)K);
}